// Round 1
// baseline (477.362 us; speedup 1.0000x reference)
//
#include <hip/hip_runtime.h>
#include <hip/hip_bf16.h>
#include <cstdint>

typedef __bf16 bf16x8 __attribute__((ext_vector_type(8)));
typedef float f32x4 __attribute__((ext_vector_type(4)));

static constexpr int S = 4096;
static constexpr int D = 768;
static constexpr int H = 12;
static constexpr int DK = 64;

__device__ __forceinline__ unsigned short f2bf(float f) {
  unsigned u = __float_as_uint(f);
  u = (u + 0x7fffu + ((u >> 16) & 1u)) >> 16;
  return (unsigned short)u;
}

// ---------------- fp32 -> bf16 conversion ----------------
__global__ void cvt_kernel(const float* __restrict__ in,
                           unsigned short* __restrict__ out, int n4) {
  int i = blockIdx.x * blockDim.x + threadIdx.x;
  if (i < n4) {
    float4 v = reinterpret_cast<const float4*>(in)[i];
    ushort4 o;
    o.x = f2bf(v.x); o.y = f2bf(v.y); o.z = f2bf(v.z); o.w = f2bf(v.w);
    reinterpret_cast<ushort4*>(out)[i] = o;
  }
}

// ---------------- QKV projection + RoPE ----------------
// C = x @ W^T (NT): A row-major [M][K], B row-major [N][K]. Both MFMA frags are
// 16B-contiguous loads. Block = 4 waves, each wave does 16 rows x 64 cols.
__global__ __launch_bounds__(256) void qkv_rope_kernel(
    const unsigned short* __restrict__ xb,
    const unsigned short* __restrict__ Wqb,
    const unsigned short* __restrict__ Wkb,
    const unsigned short* __restrict__ Wvb,
    unsigned short* __restrict__ Qh,
    unsigned short* __restrict__ Kh,
    unsigned short* __restrict__ Vh) {
  const int z = blockIdx.z;  // 0=Q,1=K,2=V
  const unsigned short* W = (z == 0) ? Wqb : (z == 1) ? Wkb : Wvb;
  unsigned short* Out = (z == 0) ? Qh : (z == 1) ? Kh : Vh;
  const int wave = threadIdx.x >> 6;
  const int lane = threadIdx.x & 63;
  const int lr = lane & 15;
  const int lk = (lane >> 4) * 8;
  const int row0 = blockIdx.x * 64 + wave * 16;
  const int col0 = blockIdx.y * 64;

  const unsigned short* arow = xb + (size_t)(row0 + lr) * D + lk;
  const unsigned short* b0 = W + (size_t)(col0 + lr) * D + lk;

  f32x4 acc[4] = {};
  for (int k = 0; k < D; k += 32) {
    bf16x8 a = *reinterpret_cast<const bf16x8*>(arow + k);
#pragma unroll
    for (int nf = 0; nf < 4; ++nf) {
      bf16x8 b = *reinterpret_cast<const bf16x8*>(b0 + (size_t)nf * 16 * D + k);
      acc[nf] = __builtin_amdgcn_mfma_f32_16x16x32_bf16(a, b, acc[nf], 0, 0, 0);
    }
  }

  const int jrow = row0 + ((lane >> 4) << 2);
#pragma unroll
  for (int nf = 0; nf < 4; ++nf) {
    const int cn = col0 + nf * 16 + lr;  // global output column
    const int hh = cn >> 6;
    const int dk = cn & 63;
    // inv_freq = theta^(-(2i)/64), 2i = dk & ~1
    const float freq = expf(-(float)(dk & ~1) * (9.210340371976184f / 64.0f));
#pragma unroll
    for (int j = 0; j < 4; ++j) {
      float v = acc[nf][j];
      const int s = jrow + j;
      if (z < 2) {
        float pv = __shfl_xor(v, 1);  // partner column (even<->odd)
        float ang = (float)s * freq;
        float si, c;
        sincosf(ang, &si, &c);
        // even col: x1*cos - x2*sin ; odd col: x1*sin + x2*cos
        v = (dk & 1) ? (pv * si + v * c) : (v * c - pv * si);
      }
      Out[((size_t)hh * S + s) * DK + dk] = f2bf(v);
    }
  }
}

// ---------------- flash attention (causal) ----------------
// grid (S/64, H); block 256 (4 waves), wave owns 16 q-rows x full d_v=64.
__global__ __launch_bounds__(256) void attn_kernel(
    const unsigned short* __restrict__ Qh,
    const unsigned short* __restrict__ Kh,
    const unsigned short* __restrict__ Vh,
    unsigned short* __restrict__ AO) {
  const int h = blockIdx.y;
  const int q0 = blockIdx.x * 64;
  const int wave = threadIdx.x >> 6;
  const int lane = threadIdx.x & 63;
  const int lr = lane & 15;
  const int lk = (lane >> 4) * 8;

  const unsigned short* Qp = Qh + (size_t)h * S * DK;
  const unsigned short* Kp = Kh + (size_t)h * S * DK;
  const __bf16* Vp = reinterpret_cast<const __bf16*>(Vh + (size_t)h * S * DK);

  const int qrow = q0 + wave * 16 + lr;
  bf16x8 qa[2];
#pragma unroll
  for (int ks = 0; ks < 2; ++ks)
    qa[ks] = *reinterpret_cast<const bf16x8*>(Qp + (size_t)qrow * DK + ks * 32 + lk);

  f32x4 o[4] = {};
  float m_[4] = {-1e30f, -1e30f, -1e30f, -1e30f};
  float l_[4] = {0.f, 0.f, 0.f, 0.f};

  // per-wave P tile, stride 72 (144B) -> only 2-way LDS bank aliasing (free)
  __shared__ alignas(16) unsigned short Plds[4][16][72];

  const int rbase = (lane >> 4) << 2;  // 0,4,8,12
  const int qg = q0 + wave * 16 + rbase;

  for (int kv0 = 0; kv0 <= q0; kv0 += 64) {
    // S = Q K^T  (K is [n][k] row-major -> NT B-frag, contiguous)
    f32x4 sc[4] = {};
#pragma unroll
    for (int ks = 0; ks < 2; ++ks) {
#pragma unroll
      for (int nf = 0; nf < 4; ++nf) {
        bf16x8 b = *reinterpret_cast<const bf16x8*>(
            Kp + (size_t)(kv0 + nf * 16 + lr) * DK + ks * 32 + lk);
        sc[nf] = __builtin_amdgcn_mfma_f32_16x16x32_bf16(qa[ks], b, sc[nf], 0, 0, 0);
      }
    }

    const int kvc = kv0 + lr;
#pragma unroll
    for (int j = 0; j < 4; ++j) {
      const int q = qg + j;
      float p[4];
      float rmax = -1e30f;
#pragma unroll
      for (int nf = 0; nf < 4; ++nf) {
        float val = sc[nf][j] * 0.125f;  // 1/sqrt(64)
        if (kvc + nf * 16 > q) val = -1e30f;  // causal mask
        p[nf] = val;
        rmax = fmaxf(rmax, val);
      }
#pragma unroll
      for (int off = 1; off < 16; off <<= 1)
        rmax = fmaxf(rmax, __shfl_xor(rmax, off));
      const float mnew = fmaxf(m_[j], rmax);
      const float sf = __expf(m_[j] - mnew);
      float rsum = 0.f;
#pragma unroll
      for (int nf = 0; nf < 4; ++nf) {
        const float pe = __expf(p[nf] - mnew);
        p[nf] = pe;
        rsum += pe;
      }
#pragma unroll
      for (int off = 1; off < 16; off <<= 1)
        rsum += __shfl_xor(rsum, off);
      l_[j] = l_[j] * sf + rsum;
      m_[j] = mnew;
#pragma unroll
      for (int nf = 0; nf < 4; ++nf) {
        o[nf][j] *= sf;
        Plds[wave][rbase + j][nf * 16 + lr] = f2bf(p[nf]);
      }
    }

    // O += P @ V   (A-frag from LDS, B-frag = V[k][n] column-ish reads)
#pragma unroll
    for (int ks = 0; ks < 2; ++ks) {
      bf16x8 pa = *reinterpret_cast<const bf16x8*>(&Plds[wave][lr][ks * 32 + lk]);
#pragma unroll
      for (int nf = 0; nf < 4; ++nf) {
        bf16x8 vb;
#pragma unroll
        for (int jj = 0; jj < 8; ++jj)
          vb[jj] = Vp[(size_t)(kv0 + ks * 32 + (lane >> 4) * 8 + jj) * DK + nf * 16 + lr];
        o[nf] = __builtin_amdgcn_mfma_f32_16x16x32_bf16(pa, vb, o[nf], 0, 0, 0);
      }
    }
  }

#pragma unroll
  for (int nf = 0; nf < 4; ++nf) {
    const int dv = nf * 16 + lr;
#pragma unroll
    for (int j = 0; j < 4; ++j) {
      const int s = qg + j;
      AO[(size_t)s * D + h * DK + dv] = f2bf(o[nf][j] / l_[j]);
    }
  }
}

// ---------------- output projection ----------------
__global__ __launch_bounds__(256) void oproj_kernel(
    const unsigned short* __restrict__ AO,
    const unsigned short* __restrict__ Wob,
    float* __restrict__ out) {
  const int wave = threadIdx.x >> 6;
  const int lane = threadIdx.x & 63;
  const int lr = lane & 15;
  const int lk = (lane >> 4) * 8;
  const int row0 = blockIdx.x * 64 + wave * 16;
  const int col0 = blockIdx.y * 64;

  const unsigned short* arow = AO + (size_t)(row0 + lr) * D + lk;
  const unsigned short* b0 = Wob + (size_t)(col0 + lr) * D + lk;

  f32x4 acc[4] = {};
  for (int k = 0; k < D; k += 32) {
    bf16x8 a = *reinterpret_cast<const bf16x8*>(arow + k);
#pragma unroll
    for (int nf = 0; nf < 4; ++nf) {
      bf16x8 b = *reinterpret_cast<const bf16x8*>(b0 + (size_t)nf * 16 * D + k);
      acc[nf] = __builtin_amdgcn_mfma_f32_16x16x32_bf16(a, b, acc[nf], 0, 0, 0);
    }
  }

  const int jrow = row0 + ((lane >> 4) << 2);
#pragma unroll
  for (int nf = 0; nf < 4; ++nf) {
    const int cn = col0 + nf * 16 + lr;
#pragma unroll
    for (int j = 0; j < 4; ++j)
      out[(size_t)(jrow + j) * D + cn] = acc[nf][j];
  }
}

extern "C" void kernel_launch(void* const* d_in, const int* in_sizes, int n_in,
                              void* d_out, int out_size, void* d_ws, size_t ws_size,
                              hipStream_t stream) {
  const float* x  = (const float*)d_in[0];
  const float* Wq = (const float*)d_in[1];
  const float* Wk = (const float*)d_in[2];
  const float* Wv = (const float*)d_in[3];
  const float* Wo = (const float*)d_in[4];
  float* out = (float*)d_out;

  char* ws = (char*)d_ws;
  unsigned short* xb  = (unsigned short*)(ws + 0);
  unsigned short* Wqb = (unsigned short*)(ws + 6291456);
  unsigned short* Wkb = (unsigned short*)(ws + 7471104);
  unsigned short* Wvb = (unsigned short*)(ws + 8650752);
  unsigned short* Wob = (unsigned short*)(ws + 9830400);
  unsigned short* Qh  = (unsigned short*)(ws + 11010048);  // [H][S][64]
  unsigned short* Kh  = (unsigned short*)(ws + 17301504);
  unsigned short* Vh  = (unsigned short*)(ws + 23592960);
  unsigned short* AO  = (unsigned short*)(ws + 29884416);  // [S][D]

  const int nx = S * D;   // 3145728
  const int nw = D * D;   // 589824
  cvt_kernel<<<(nx / 4 + 255) / 256, 256, 0, stream>>>(x, xb, nx / 4);
  cvt_kernel<<<(nw / 4 + 255) / 256, 256, 0, stream>>>(Wq, Wqb, nw / 4);
  cvt_kernel<<<(nw / 4 + 255) / 256, 256, 0, stream>>>(Wk, Wkb, nw / 4);
  cvt_kernel<<<(nw / 4 + 255) / 256, 256, 0, stream>>>(Wv, Wvb, nw / 4);
  cvt_kernel<<<(nw / 4 + 255) / 256, 256, 0, stream>>>(Wo, Wob, nw / 4);

  qkv_rope_kernel<<<dim3(64, 12, 3), 256, 0, stream>>>(xb, Wqb, Wkb, Wvb, Qh, Kh, Vh);
  attn_kernel<<<dim3(64, 12), 256, 0, stream>>>(Qh, Kh, Vh, AO);
  oproj_kernel<<<dim3(64, 12), 256, 0, stream>>>(AO, Wob, out);
}

// Round 3
// 405.943 us; speedup vs baseline: 1.1759x; 1.1759x over previous
//
#include <hip/hip_runtime.h>
#include <hip/hip_bf16.h>
#include <cstdint>

typedef __bf16 bf16x8 __attribute__((ext_vector_type(8)));
typedef float f32x4 __attribute__((ext_vector_type(4)));

static constexpr int S = 4096;
static constexpr int D = 768;
static constexpr int H = 12;
static constexpr int DK = 64;

__device__ __forceinline__ unsigned short f2bf(float f) {
  unsigned u = __float_as_uint(f);
  u = (u + 0x7fffu + ((u >> 16) & 1u)) >> 16;
  return (unsigned short)u;
}

// ---------------- fp32 -> bf16 conversion ----------------
__global__ void cvt_kernel(const float* __restrict__ in,
                           unsigned short* __restrict__ out, int n4) {
  int i = blockIdx.x * blockDim.x + threadIdx.x;
  if (i < n4) {
    float4 v = reinterpret_cast<const float4*>(in)[i];
    ushort4 o;
    o.x = f2bf(v.x); o.y = f2bf(v.y); o.z = f2bf(v.z); o.w = f2bf(v.w);
    reinterpret_cast<ushort4*>(out)[i] = o;
  }
}

// ---------------- QKV projection + RoPE (+ V transpose) ----------------
// C = x @ W^T (NT). Block = 4 waves x 32 rows = 128 rows, 64 cols.
// grid (S/128, D/64, 3). For z==2 (V) the 64 output cols = one full head;
// epilogue transposes the 128x64 tile through LDS and stores Vt[h][dk][s].
__global__ __launch_bounds__(256) void qkv_rope_kernel(
    const unsigned short* __restrict__ xb,
    const unsigned short* __restrict__ Wqb,
    const unsigned short* __restrict__ Wkb,
    const unsigned short* __restrict__ Wvb,
    unsigned short* __restrict__ Qh,
    unsigned short* __restrict__ Kh,
    unsigned short* __restrict__ Vt) {
  const int z = blockIdx.z;  // 0=Q,1=K,2=V
  const unsigned short* W = (z == 0) ? Wqb : (z == 1) ? Wkb : Wvb;
  const int wave = threadIdx.x >> 6;
  const int lane = threadIdx.x & 63;
  const int lr = lane & 15;
  const int hi = lane >> 4;
  const int lk = hi * 8;
  const int row0 = blockIdx.x * 128 + wave * 32;
  const int col0 = blockIdx.y * 64;

  const unsigned short* a0 = xb + (size_t)(row0 + lr) * D + lk;
  const unsigned short* b0 = W + (size_t)(col0 + lr) * D + lk;

  __shared__ unsigned short tlds[64][136];  // V-transpose staging (z==2 only)

  f32x4 acc[2][4] = {};
  for (int k = 0; k < D; k += 32) {
    bf16x8 a[2];
#pragma unroll
    for (int rf = 0; rf < 2; ++rf)
      a[rf] = *reinterpret_cast<const bf16x8*>(a0 + (size_t)rf * 16 * D + k);
#pragma unroll
    for (int nf = 0; nf < 4; ++nf) {
      bf16x8 b = *reinterpret_cast<const bf16x8*>(b0 + (size_t)nf * 16 * D + k);
#pragma unroll
      for (int rf = 0; rf < 2; ++rf)
        acc[rf][nf] = __builtin_amdgcn_mfma_f32_16x16x32_bf16(a[rf], b, acc[rf][nf], 0, 0, 0);
    }
  }

  if (z < 2) {
    unsigned short* Out = (z == 0) ? Qh : Kh;
#pragma unroll
    for (int nf = 0; nf < 4; ++nf) {
      const int cn = col0 + nf * 16 + lr;
      const int hh = cn >> 6;
      const int dk = cn & 63;
      const float freq = expf(-(float)(dk & ~1) * (9.210340371976184f / 64.0f));
#pragma unroll
      for (int rf = 0; rf < 2; ++rf) {
        const int jrow = row0 + rf * 16 + hi * 4;
#pragma unroll
        for (int j = 0; j < 4; ++j) {
          float v = acc[rf][nf][j];
          const int s = jrow + j;
          float pv = __shfl_xor(v, 1);  // partner column (even<->odd)
          float ang = (float)s * freq;
          float si, c;
          sincosf(ang, &si, &c);
          v = (dk & 1) ? (pv * si + v * c) : (v * c - pv * si);
          Out[((size_t)hh * S + s) * DK + dk] = f2bf(v);
        }
      }
    }
  } else {
    // stage transposed into LDS: tlds[dk][s_local]
#pragma unroll
    for (int nf = 0; nf < 4; ++nf) {
      const int dk = nf * 16 + lr;
#pragma unroll
      for (int rf = 0; rf < 2; ++rf) {
        const int sl = wave * 32 + rf * 16 + hi * 4;
#pragma unroll
        for (int j = 0; j < 4; ++j)
          tlds[dk][sl + j] = f2bf(acc[rf][nf][j]);
      }
    }
    __syncthreads();
    // coalesced write-out: Vt[(h*64+dk)*S + s]
    const int h = blockIdx.y;
    const int dk = threadIdx.x >> 2;
    const int ch = threadIdx.x & 3;
    const int s0 = blockIdx.x * 128 + ch * 32;
    unsigned short* dst = Vt + ((size_t)h * 64 + dk) * S + s0;
#pragma unroll
    for (int u = 0; u < 4; ++u) {
      bf16x8 v = *reinterpret_cast<const bf16x8*>(&tlds[dk][ch * 32 + u * 8]);
      *reinterpret_cast<bf16x8*>(dst + u * 8) = v;
    }
  }
}

// ---------------- flash attention (causal) ----------------
// grid (S/128, H); block 256 (4 waves), wave owns 32 q-rows x full d_v=64.
// q-blocks dispatched heavy-first (reversed) for causal load balance.
__global__ __launch_bounds__(256) void attn_kernel(
    const unsigned short* __restrict__ Qh,
    const unsigned short* __restrict__ Kh,
    const unsigned short* __restrict__ Vt,
    unsigned short* __restrict__ AO) {
  const int h = blockIdx.y;
  const int qb = gridDim.x - 1 - blockIdx.x;  // heavy blocks first
  const int q0 = qb * 128;
  const int wave = threadIdx.x >> 6;
  const int lane = threadIdx.x & 63;
  const int lr = lane & 15;
  const int hi = lane >> 4;
  const int lk = hi * 8;
  const int rbase = hi * 4;

  const unsigned short* Qp = Qh + (size_t)h * S * DK;
  const unsigned short* Kp = Kh + (size_t)h * S * DK;
  const unsigned short* Vtp = Vt + (size_t)h * DK * S;

  const int q0w = q0 + wave * 32;
  bf16x8 qa[2][2];
#pragma unroll
  for (int rf = 0; rf < 2; ++rf)
#pragma unroll
    for (int ks = 0; ks < 2; ++ks)
      qa[rf][ks] = *reinterpret_cast<const bf16x8*>(
          Qp + (size_t)(q0w + rf * 16 + lr) * DK + ks * 32 + lk);

  f32x4 o[2][4] = {};
  float m_[2][4], l_[2][4];
#pragma unroll
  for (int rf = 0; rf < 2; ++rf)
#pragma unroll
    for (int j = 0; j < 4; ++j) { m_[rf][j] = -1e30f; l_[rf][j] = 0.f; }

  __shared__ alignas(16) unsigned short Plds[4][32][72];

  const int kvmax = ((q0w + 31) >> 6) << 6;
  for (int kv0 = 0; kv0 <= kvmax; kv0 += 64) {
    // S = Q K^T
    f32x4 sc[2][4] = {};
#pragma unroll
    for (int ks = 0; ks < 2; ++ks) {
      bf16x8 kb[4];
#pragma unroll
      for (int nf = 0; nf < 4; ++nf)
        kb[nf] = *reinterpret_cast<const bf16x8*>(
            Kp + (size_t)(kv0 + nf * 16 + lr) * DK + ks * 32 + lk);
#pragma unroll
      for (int rf = 0; rf < 2; ++rf)
#pragma unroll
        for (int nf = 0; nf < 4; ++nf)
          sc[rf][nf] = __builtin_amdgcn_mfma_f32_16x16x32_bf16(qa[rf][ks], kb[nf], sc[rf][nf], 0, 0, 0);
    }

    const bool full = (kv0 + 63) < q0w;  // strictly below diagonal: no mask
    const int kvc = kv0 + lr;
#pragma unroll
    for (int rf = 0; rf < 2; ++rf) {
      const int qg = q0w + rf * 16 + rbase;
#pragma unroll
      for (int j = 0; j < 4; ++j) {
        const int q = qg + j;
        float p[4];
        float rmax = -1e30f;
#pragma unroll
        for (int nf = 0; nf < 4; ++nf) {
          float val = sc[rf][nf][j] * 0.125f;  // 1/sqrt(64)
          if (!full && kvc + nf * 16 > q) val = -1e30f;
          p[nf] = val;
          rmax = fmaxf(rmax, val);
        }
#pragma unroll
        for (int off = 1; off < 16; off <<= 1)
          rmax = fmaxf(rmax, __shfl_xor(rmax, off));
        const float mnew = fmaxf(m_[rf][j], rmax);
        const float sf = __expf(m_[rf][j] - mnew);
        float rsum = 0.f;
#pragma unroll
        for (int nf = 0; nf < 4; ++nf) {
          const float pe = __expf(p[nf] - mnew);
          p[nf] = pe;
          rsum += pe;
        }
#pragma unroll
        for (int off = 1; off < 16; off <<= 1)
          rsum += __shfl_xor(rsum, off);
        l_[rf][j] = l_[rf][j] * sf + rsum;
        m_[rf][j] = mnew;
#pragma unroll
        for (int nf = 0; nf < 4; ++nf) {
          o[rf][nf][j] *= sf;  // FIX: per-row rescale (was whole-f32x4 in r1)
          Plds[wave][rf * 16 + rbase + j][nf * 16 + lr] = f2bf(p[nf]);
        }
      }
    }

    // O += P @ V  (B-frags contiguous from Vt)
#pragma unroll
    for (int ks = 0; ks < 2; ++ks) {
      bf16x8 pa[2];
#pragma unroll
      for (int rf = 0; rf < 2; ++rf)
        pa[rf] = *reinterpret_cast<const bf16x8*>(&Plds[wave][rf * 16 + lr][ks * 32 + lk]);
      bf16x8 vb[4];
#pragma unroll
      for (int nf = 0; nf < 4; ++nf)
        vb[nf] = *reinterpret_cast<const bf16x8*>(
            Vtp + (size_t)(nf * 16 + lr) * S + kv0 + ks * 32 + lk);
#pragma unroll
      for (int rf = 0; rf < 2; ++rf)
#pragma unroll
        for (int nf = 0; nf < 4; ++nf)
          o[rf][nf] = __builtin_amdgcn_mfma_f32_16x16x32_bf16(pa[rf], vb[nf], o[rf][nf], 0, 0, 0);
    }
  }

#pragma unroll
  for (int rf = 0; rf < 2; ++rf)
#pragma unroll
    for (int nf = 0; nf < 4; ++nf) {
      const int dv = nf * 16 + lr;
#pragma unroll
      for (int j = 0; j < 4; ++j) {
        const int s = q0w + rf * 16 + rbase + j;
        AO[(size_t)s * D + h * DK + dv] = f2bf(o[rf][nf][j] / l_[rf][j]);
      }
    }
}

// ---------------- output projection ----------------
__global__ __launch_bounds__(256) void oproj_kernel(
    const unsigned short* __restrict__ AO,
    const unsigned short* __restrict__ Wob,
    float* __restrict__ out) {
  const int wave = threadIdx.x >> 6;
  const int lane = threadIdx.x & 63;
  const int lr = lane & 15;
  const int hi = lane >> 4;
  const int lk = hi * 8;
  const int row0 = blockIdx.x * 128 + wave * 32;
  const int col0 = blockIdx.y * 64;

  const unsigned short* a0 = AO + (size_t)(row0 + lr) * D + lk;
  const unsigned short* b0 = Wob + (size_t)(col0 + lr) * D + lk;

  f32x4 acc[2][4] = {};
  for (int k = 0; k < D; k += 32) {
    bf16x8 a[2];
#pragma unroll
    for (int rf = 0; rf < 2; ++rf)
      a[rf] = *reinterpret_cast<const bf16x8*>(a0 + (size_t)rf * 16 * D + k);
#pragma unroll
    for (int nf = 0; nf < 4; ++nf) {
      bf16x8 b = *reinterpret_cast<const bf16x8*>(b0 + (size_t)nf * 16 * D + k);
#pragma unroll
      for (int rf = 0; rf < 2; ++rf)
        acc[rf][nf] = __builtin_amdgcn_mfma_f32_16x16x32_bf16(a[rf], b, acc[rf][nf], 0, 0, 0);
    }
  }

#pragma unroll
  for (int rf = 0; rf < 2; ++rf) {
    const int jrow = row0 + rf * 16 + hi * 4;
#pragma unroll
    for (int nf = 0; nf < 4; ++nf) {
      const int cn = col0 + nf * 16 + lr;
#pragma unroll
      for (int j = 0; j < 4; ++j)
        out[(size_t)(jrow + j) * D + cn] = acc[rf][nf][j];
    }
  }
}

extern "C" void kernel_launch(void* const* d_in, const int* in_sizes, int n_in,
                              void* d_out, int out_size, void* d_ws, size_t ws_size,
                              hipStream_t stream) {
  const float* x  = (const float*)d_in[0];
  const float* Wq = (const float*)d_in[1];
  const float* Wk = (const float*)d_in[2];
  const float* Wv = (const float*)d_in[3];
  const float* Wo = (const float*)d_in[4];
  float* out = (float*)d_out;

  char* ws = (char*)d_ws;
  unsigned short* xb  = (unsigned short*)(ws + 0);
  unsigned short* Wqb = (unsigned short*)(ws + 6291456);
  unsigned short* Wkb = (unsigned short*)(ws + 7471104);
  unsigned short* Wvb = (unsigned short*)(ws + 8650752);
  unsigned short* Wob = (unsigned short*)(ws + 9830400);
  unsigned short* Qh  = (unsigned short*)(ws + 11010048);  // [H][S][64]
  unsigned short* Kh  = (unsigned short*)(ws + 17301504);  // [H][S][64]
  unsigned short* Vt  = (unsigned short*)(ws + 23592960);  // [H][64][S]
  unsigned short* AO  = (unsigned short*)(ws + 29884416);  // [S][D]

  const int nx = S * D;   // 3145728
  const int nw = D * D;   // 589824
  cvt_kernel<<<(nx / 4 + 255) / 256, 256, 0, stream>>>(x, xb, nx / 4);
  cvt_kernel<<<(nw / 4 + 255) / 256, 256, 0, stream>>>(Wq, Wqb, nw / 4);
  cvt_kernel<<<(nw / 4 + 255) / 256, 256, 0, stream>>>(Wk, Wkb, nw / 4);
  cvt_kernel<<<(nw / 4 + 255) / 256, 256, 0, stream>>>(Wv, Wvb, nw / 4);
  cvt_kernel<<<(nw / 4 + 255) / 256, 256, 0, stream>>>(Wo, Wob, nw / 4);

  qkv_rope_kernel<<<dim3(32, 12, 3), 256, 0, stream>>>(xb, Wqb, Wkb, Wvb, Qh, Kh, Vt);
  attn_kernel<<<dim3(32, 12), 256, 0, stream>>>(Qh, Kh, Vt, AO);
  oproj_kernel<<<dim3(32, 12), 256, 0, stream>>>(AO, Wob, out);
}